// Round 9
// baseline (386.261 us; speedup 1.0000x reference)
//
#include <hip/hip_runtime.h>
#include <hip/hip_bf16.h>
#include <stdint.h>

#define N_NODES 50000
#define N_EDGES 800000
#define HIDDEN  128
#define HEADS   4
#define HD      (HEADS*HIDDEN)   // 512
#define CAST_Q  (N_NODES*HIDDEN/4)   // 1,600,000 float4 quads of x
#define NTILES  (N_NODES/16)         // 3125 (exact)

typedef __attribute__((ext_vector_type(8))) short  short8;
typedef __attribute__((ext_vector_type(4))) float  floatx4;
typedef __attribute__((ext_vector_type(2))) float  floatx2;

static __device__ __forceinline__ unsigned short bf16_bits(float f) {
    __hip_bfloat16 h = __float2bfloat16(f);
    union { __hip_bfloat16 b; unsigned short s; } u; u.b = h; return u.s;
}

// leaky_relu(a, 0.2) == max(a, 0.2a); then fast exp
static __device__ __forceinline__ float lexp(float a) {
    return __expf(fmaxf(a, 0.2f * a));
}

// ---------------- fp8 e4m3 encode/decode (HW cvt when available) ----------------

#if __has_builtin(__builtin_amdgcn_cvt_pk_fp8_f32) && __has_builtin(__builtin_amdgcn_cvt_pk_f32_fp8)
#define FP8_HW 1
#else
#define FP8_HW 0
static __device__ __forceinline__ unsigned fp8_enc1(float f) {
    unsigned s = __float_as_uint(f) >> 31;
    float a = fabsf(f);
    if (a < 0.0009765625f) return s << 7;
    if (a > 448.f) a = 448.f;
    unsigned ub = __float_as_uint(a) + 0x00080000u;  // round at bit19
    int e = (int)((ub >> 23) & 255) - 120;           // biased-7 exponent
    unsigned m = (ub >> 20) & 7;
    if (e <= 0) {
        int mm = (int)(a * 512.f + 0.5f); if (mm > 7) mm = 7;
        return (s << 7) | (unsigned)mm;
    }
    if (e > 15) { e = 15; m = 7; }
    return (s << 7) | ((unsigned)e << 3) | m;
}
static __device__ __forceinline__ float fp8_dec1(unsigned b) {
    unsigned s = (b >> 7) & 1, e = (b >> 3) & 15, m = b & 7;
    if (e == 0) { float f = (float)m * 0.001953125f; return s ? -f : f; }
    return __uint_as_float((s << 31) | ((e + 120) << 23) | (m << 20));
}
#endif

static __device__ __forceinline__ unsigned fp8_pack4(float a, float b, float c, float d) {
#if FP8_HW
    int w = __builtin_amdgcn_cvt_pk_fp8_f32(a, b, 0, false);
    w     = __builtin_amdgcn_cvt_pk_fp8_f32(c, d, w, true);
    return (unsigned)w;
#else
    return fp8_enc1(a) | (fp8_enc1(b) << 8) | (fp8_enc1(c) << 16) | (fp8_enc1(d) << 24);
#endif
}

static __device__ __forceinline__ void accf8(float* acc, uint2 u, float wt) {
#if FP8_HW
    floatx2 f;
    f = __builtin_amdgcn_cvt_pk_f32_fp8((int)u.x, false); acc[0] += wt * f.x; acc[1] += wt * f.y;
    f = __builtin_amdgcn_cvt_pk_f32_fp8((int)u.x, true);  acc[2] += wt * f.x; acc[3] += wt * f.y;
    f = __builtin_amdgcn_cvt_pk_f32_fp8((int)u.y, false); acc[4] += wt * f.x; acc[5] += wt * f.y;
    f = __builtin_amdgcn_cvt_pk_f32_fp8((int)u.y, true);  acc[6] += wt * f.x; acc[7] += wt * f.y;
#else
    acc[0] += wt * fp8_dec1(u.x & 255);         acc[1] += wt * fp8_dec1((u.x >> 8) & 255);
    acc[2] += wt * fp8_dec1((u.x >> 16) & 255); acc[3] += wt * fp8_dec1(u.x >> 24);
    acc[4] += wt * fp8_dec1(u.y & 255);         acc[5] += wt * fp8_dec1((u.y >> 8) & 255);
    acc[6] += wt * fp8_dec1((u.y >> 16) & 255); acc[7] += wt * fp8_dec1(u.y >> 24);
#endif
}

// ---------------- prep: x fp32->bf16 cast + weight swizzle, one launch ----------------
// fragment element (kc,nt,q,r,j) at offset ((kc*(N/16)+nt)*4+q)*128 + r*8 + j
// natural source row kr = kc*32+q*8+j, col = nt*16+r.
// proj_w rows PERMUTED (kr -> (kr&7)*16 + (kr>>3)) to compensate rc's [r][ntl] layout.

__global__ __launch_bounds__(256) void prep_k(
        const float* __restrict__ x, unsigned short* __restrict__ xb16,
        const float* __restrict__ conv_w, const float* __restrict__ proj_w,
        const float* __restrict__ skip_w,
        unsigned short* __restrict__ cwb, unsigned short* __restrict__ pwb,
        unsigned short* __restrict__ swb) {
    int i = blockIdx.x * 256 + threadIdx.x;
    if (i < CAST_Q) {
        float4 v = ((const float4*)x)[i];
        uint2 p;
        p.x = (unsigned)bf16_bits(v.x) | ((unsigned)bf16_bits(v.y) << 16);
        p.y = (unsigned)bf16_bits(v.z) | ((unsigned)bf16_bits(v.w) << 16);
        ((uint2*)xb16)[i] = p;
        return;
    }
    int o = i - CAST_Q;
    const float* B; unsigned short* D; int off, N; bool perm = false;
    if (o < 131072)      { B = conv_w + (o >> 16) * 65536; D = cwb + (o >> 16) * 65536; off = o & 65535; N = 512; }
    else if (o < 163840) { int t = o - 131072; B = proj_w + (t >> 14) * 16384; D = pwb + (t >> 14) * 16384; off = t & 16383; N = 128; perm = true; }
    else if (o < 196608) { int t = o - 163840; B = skip_w + (t >> 14) * 16384; D = swb + (t >> 14) * 16384; off = t & 16383; N = 128; }
    else return;
    int j = off & 7, r = (off >> 3) & 15, q = (off >> 7) & 3;
    int rest = off >> 9, ntn = N >> 4;
    int nt = rest % ntn, kc = rest / ntn;
    int kr = kc * 32 + q * 8 + j;
    int row = perm ? ((kr & 7) * 16 + (kr >> 3)) : kr;
    D[off] = bf16_bits(B[(size_t)row * N + nt * 16 + r]);
}

// ---------------- CSR build ----------------

__global__ __launch_bounds__(256) void hist_k(const int* __restrict__ dst,
                                              int* __restrict__ cnt, int E) {
    int e = blockIdx.x * 256 + threadIdx.x;
    if (e < E) atomicAdd(&cnt[dst[e]], 1);
}

__global__ __launch_bounds__(1024) void scan1_k(const int* __restrict__ cnt,
                                                int* __restrict__ row_ptr,
                                                int* __restrict__ bsum, int n) {
    __shared__ int buf[1024];
    int t = threadIdx.x, i = blockIdx.x * 1024 + t;
    int v = (i < n) ? cnt[i] : 0;
    buf[t] = v;
    __syncthreads();
    for (int off = 1; off < 1024; off <<= 1) {
        int xv = (t >= off) ? buf[t - off] : 0;
        __syncthreads();
        buf[t] += xv;
        __syncthreads();
    }
    if (i < n) row_ptr[i] = buf[t] - v;
    if (t == 1023) bsum[blockIdx.x] = buf[1023];
}

__global__ void scan2_k(int* __restrict__ bsum, int nb) {
    if (threadIdx.x == 0) {
        int acc = 0;
        for (int i = 0; i < nb; ++i) { int v = bsum[i]; bsum[i] = acc; acc += v; }
    }
}

__global__ __launch_bounds__(1024) void scan3_k(int* __restrict__ row_ptr,
                                                const int* __restrict__ bsum, int n, int E) {
    int i = blockIdx.x * 1024 + threadIdx.x;
    if (i < n) row_ptr[i] += bsum[blockIdx.x];
    if (i == 0) row_ptr[n] = E;
}

__global__ __launch_bounds__(256) void scatter_k(const int* __restrict__ src,
                                                 const int* __restrict__ dst,
                                                 const int* __restrict__ row_ptr,
                                                 int* __restrict__ fill,
                                                 int* __restrict__ src_sorted, int E) {
    int e = blockIdx.x * 256 + threadIdx.x;
    if (e >= E) return;
    int d = dst[e];
    int p = row_ptr[d] + atomicAdd(&fill[d], 1);
    src_sorted[p] = src[e];
}

// ---------------- conv GEMM: h8 = fp8(A@conv_w), B-in-registers, fused alpha ----------------
// h8 row layout (bytes): [head][r][ntl]; natural channel ntl*16+r at byte r*8+ntl of head slice.

__global__ __launch_bounds__(256, 2) void gemmc_k(
        const __hip_bfloat16* __restrict__ A,      // M x 128 bf16 (natural)
        const unsigned short* __restrict__ Bs,     // swizzled 128x512
        const float* __restrict__ att_s, const float* __restrict__ att_d,
        unsigned char* __restrict__ h8,
        float* __restrict__ a_src, float* __restrict__ a_dst, int mtiles) {
    int head = threadIdx.x >> 6;
    int lane = threadIdx.x & 63;
    int r = lane & 15, q = lane >> 4;

    short8 Bf[4][8];
#pragma unroll
    for (int kc = 0; kc < 4; ++kc)
#pragma unroll
        for (int ntl = 0; ntl < 8; ++ntl)
            Bf[kc][ntl] = *(const short8*)((const short*)Bs +
                (((size_t)(kc * 32 + head * 8 + ntl) * 4 + q) * 128 + r * 8));

    float as_r[8], ad_r[8];
#pragma unroll
    for (int ntl = 0; ntl < 8; ++ntl) {
        as_r[ntl] = att_s[head * HIDDEN + ntl * 16 + r];
        ad_r[ntl] = att_d[head * HIDDEN + ntl * 16 + r];
    }

    for (int mt = blockIdx.x; mt < mtiles; mt += gridDim.x) {
        int m0 = mt * 16;
        const short* Ab = (const short*)A + (size_t)(m0 + r) * HIDDEN + q * 8;
        short8 av[4];
#pragma unroll
        for (int kc = 0; kc < 4; ++kc) av[kc] = *(const short8*)(Ab + kc * 32);

        floatx4 acc[8];
#pragma unroll
        for (int i = 0; i < 8; ++i) acc[i] = (floatx4){0.f, 0.f, 0.f, 0.f};
#pragma unroll
        for (int kc = 0; kc < 4; ++kc)
#pragma unroll
            for (int ntl = 0; ntl < 8; ++ntl)
                acc[ntl] = __builtin_amdgcn_mfma_f32_16x16x32_bf16(av[kc], Bf[kc][ntl], acc[ntl], 0, 0, 0);

        // store h8: row q*4+i, 8 B per row per lane
#pragma unroll
        for (int i = 0; i < 4; ++i) {
            uint2 o;
            o.x = fp8_pack4(acc[0][i], acc[1][i], acc[2][i], acc[3][i]);
            o.y = fp8_pack4(acc[4][i], acc[5][i], acc[6][i], acc[7][i]);
            *(uint2*)(h8 + (size_t)(m0 + q * 4 + i) * HD + head * HIDDEN + r * 8) = o;
        }
        // fused alpha (fp32 accumulators — full precision)
        float sA[4] = {0, 0, 0, 0}, sD[4] = {0, 0, 0, 0};
#pragma unroll
        for (int ntl = 0; ntl < 8; ++ntl)
#pragma unroll
            for (int i = 0; i < 4; ++i) {
                sA[i] += acc[ntl][i] * as_r[ntl];
                sD[i] += acc[ntl][i] * ad_r[ntl];
            }
#pragma unroll
        for (int d = 1; d < 16; d <<= 1)
#pragma unroll
            for (int i = 0; i < 4; ++i) {
                sA[i] += __shfl_xor(sA[i], d);
                sD[i] += __shfl_xor(sD[i], d);
            }
        if (r == 0)
#pragma unroll
            for (int i = 0; i < 4; ++i) {
                int row = m0 + q * 4 + i;
                a_src[row * HEADS + head] = sA[i];
                a_dst[row * HEADS + head] = sD[i];
            }
    }
}

// ---------------- FUSED msg + proj/skip GEMM: one block per 16-node tile ----------------
// Phase 1: wave w aggregates nodes tile*16 + w*4 + {0..3} (msg loop, fp8 h gather),
//          writes relu(mean+bias) rows into LDS (permuted [r][ntl] layout, row pad 16B).
// Phase 2: dual GEMM D = rc_lds@pwb + xc@swb + b1 + b2; wave w owns coltiles {2w, 2w+1}.

template <typename OutT>
__global__ __launch_bounds__(256) void mp_k(
        const int* __restrict__ row_ptr, const int* __restrict__ src_sorted,
        const float* __restrict__ a_src, const float* __restrict__ a_dst,
        const unsigned char* __restrict__ h8, const float* __restrict__ conv_b,
        const unsigned short* __restrict__ Bs,   // pwb (row-permuted swizzle)
        const __hip_bfloat16* __restrict__ A2,   // xc (layer input, natural)
        const unsigned short* __restrict__ Bs2,  // swb
        const float* __restrict__ b1, const float* __restrict__ b2,
        OutT* __restrict__ D) {
    __shared__ uint4 lds[16 * 17];               // 16 rows x (16 uint4 + 1 pad)
    int wave = threadIdx.x >> 6;
    int lane = threadIdx.x & 63;
    int head = lane >> 4;
    int r = lane & 15, q = lane >> 4;
    int m0 = blockIdx.x * 16;
    const uint2* hq = (const uint2*)h8;

    // ---- phase 1: 4 nodes per wave ----
    for (int i = 0; i < 4; ++i) {
        int li = wave * 4 + i;                   // local row 0..15
        int n = m0 + li;
        float adn = a_dst[n * HEADS + head];
        int beg = row_ptr[n], end = row_ptr[n + 1];

        float acc[8] = {0.f, 0.f, 0.f, 0.f, 0.f, 0.f, 0.f, 0.f};
        float esum = 0.f;
        for (int base = beg; base < end; base += 32) {
            int m = min(32, end - base);
            int sv = (lane < m) ? src_sorted[base + lane] : 0;
            int j = 0;
            for (; j + 4 <= m; j += 4) {
                int s0 = __shfl(sv, j),     s1 = __shfl(sv, j + 1);
                int s2 = __shfl(sv, j + 2), s3 = __shfl(sv, j + 3);
                uint2 u0 = hq[(size_t)s0 * 64 + lane];
                uint2 u1 = hq[(size_t)s1 * 64 + lane];
                uint2 u2 = hq[(size_t)s2 * 64 + lane];
                uint2 u3 = hq[(size_t)s3 * 64 + lane];
                float e0 = lexp(a_src[s0 * 4 + head] + adn);
                float e1 = lexp(a_src[s1 * 4 + head] + adn);
                float e2 = lexp(a_src[s2 * 4 + head] + adn);
                float e3 = lexp(a_src[s3 * 4 + head] + adn);
                accf8(acc, u0, e0);
                accf8(acc, u1, e1);
                accf8(acc, u2, e2);
                accf8(acc, u3, e3);
                esum += (e0 + e1) + (e2 + e3);
            }
            for (; j < m; ++j) {
                int s0 = __shfl(sv, j);
                uint2 u0 = hq[(size_t)s0 * 64 + lane];
                float e0 = lexp(a_src[s0 * 4 + head] + adn);
                accf8(acc, u0, e0);
                esum += e0;
            }
        }
        float rinv = 1.f / (esum + 1e-16f);
#pragma unroll
        for (int k = 0; k < 8; ++k) acc[k] *= rinv;
#pragma unroll
        for (int k = 0; k < 8; ++k) {
            acc[k] += __shfl_xor(acc[k], 16);
            acc[k] += __shfl_xor(acc[k], 32);
        }
        if (lane < 16) {
            union { uint4 v; unsigned short us[8]; } o;
#pragma unroll
            for (int k = 0; k < 8; ++k) {
                float mres = 0.25f * acc[k] + conv_b[k * 16 + lane];
                o.us[k] = bf16_bits(mres > 0.f ? mres : 0.f);
            }
            lds[li * 17 + lane] = o.v;           // permuted [r][ntl] row
        }
    }
    __syncthreads();

    // ---- phase 2: dual GEMM, wave owns coltiles ct = 2*wave + {0,1} ----
    short8 av[4], av2[4];
#pragma unroll
    for (int kc = 0; kc < 4; ++kc) {
        av[kc] = *(const short8*)&lds[r * 17 + kc * 4 + q];   // ds_read_b128, 2-way aliasing
        av2[kc] = *(const short8*)((const short*)A2 + (size_t)(m0 + r) * HIDDEN + q * 8 + kc * 32);
    }
#pragma unroll
    for (int c = 0; c < 2; ++c) {
        int ct = wave * 2 + c;
        floatx4 acc = (floatx4){0.f, 0.f, 0.f, 0.f};
#pragma unroll
        for (int kc = 0; kc < 4; ++kc) {
            size_t off = (((size_t)(kc * 8 + ct) * 4 + q) * 128 + r * 8);
            short8 bv  = *(const short8*)((const short*)Bs  + off);
            short8 bv2 = *(const short8*)((const short*)Bs2 + off);
            acc = __builtin_amdgcn_mfma_f32_16x16x32_bf16(av[kc],  bv,  acc, 0, 0, 0);
            acc = __builtin_amdgcn_mfma_f32_16x16x32_bf16(av2[kc], bv2, acc, 0, 0, 0);
        }
        int col = ct * 16 + r;
        float bias = b1[col] + b2[col];
#pragma unroll
        for (int i = 0; i < 4; ++i) {
            int row = m0 + q * 4 + i;
            float v = acc[i] + bias;
            if constexpr (sizeof(OutT) == 4)
                ((float*)D)[(size_t)row * HIDDEN + col] = v;
            else
                ((__hip_bfloat16*)D)[(size_t)row * HIDDEN + col] = __float2bfloat16(v);
        }
    }
}

// ---------------- launcher ----------------

extern "C" void kernel_launch(void* const* d_in, const int* in_sizes, int n_in,
                              void* d_out, int out_size, void* d_ws, size_t ws_size,
                              hipStream_t stream) {
    const float* x      = (const float*)d_in[0];
    const int*   ei     = (const int*)d_in[1];
    const float* conv_w = (const float*)d_in[2];
    const float* att_s  = (const float*)d_in[3];
    const float* att_d  = (const float*)d_in[4];
    const float* conv_b = (const float*)d_in[5];
    const float* proj_w = (const float*)d_in[6];
    const float* proj_b = (const float*)d_in[7];
    const float* skip_w = (const float*)d_in[8];
    const float* skip_b = (const float*)d_in[9];
    float* out = (float*)d_out;

    char* ws = (char*)d_ws;
    size_t o = 0;
    auto alloc = [&](size_t b) { size_t c = o; o += (b + 255) & ~(size_t)255; return c; };
    __hip_bfloat16* xb16 = (__hip_bfloat16*)(ws + alloc((size_t)N_NODES * HIDDEN * 2));
    unsigned short* cwb  = (unsigned short*)(ws + alloc((size_t)2 * HIDDEN * HD * 2));
    unsigned short* pwb  = (unsigned short*)(ws + alloc((size_t)2 * HIDDEN * HIDDEN * 2));
    unsigned short* swb  = (unsigned short*)(ws + alloc((size_t)2 * HIDDEN * HIDDEN * 2));
    unsigned char* h8    = (unsigned char*)(ws + alloc((size_t)N_NODES * HD));
    float* a_src         = (float*)(ws + alloc((size_t)N_NODES * HEADS * 4));
    float* a_dst         = (float*)(ws + alloc((size_t)N_NODES * HEADS * 4));
    int* row_ptr         = (int*)(ws + alloc((size_t)(N_NODES + 1) * 4));
    int* cntfill         = (int*)(ws + alloc((size_t)2 * N_NODES * 4));
    int* cnt  = cntfill;
    int* fill = cntfill + N_NODES;
    int* src_s           = (int*)(ws + alloc((size_t)N_EDGES * 4));
    __hip_bfloat16* xb   = (__hip_bfloat16*)(ws + alloc((size_t)N_NODES * HIDDEN * 2));
    int* bsum            = (int*)(ws + alloc(64 * 4));

    const int* srcp = ei;
    const int* dstp = ei + N_EDGES;

    (void)hipMemsetAsync(cntfill, 0, (size_t)2 * N_NODES * 4, stream);

    prep_k<<<(CAST_Q + 196608 + 255) / 256, 256, 0, stream>>>(
        x, (unsigned short*)xb16, conv_w, proj_w, skip_w, cwb, pwb, swb);

    hist_k<<<(N_EDGES + 255) / 256, 256, 0, stream>>>(dstp, cnt, N_EDGES);
    const int nb = (N_NODES + 1023) / 1024;  // 49
    scan1_k<<<nb, 1024, 0, stream>>>(cnt, row_ptr, bsum, N_NODES);
    scan2_k<<<1, 64, 0, stream>>>(bsum, nb);
    scan3_k<<<nb, 1024, 0, stream>>>(row_ptr, bsum, N_NODES, N_EDGES);
    scatter_k<<<(N_EDGES + 255) / 256, 256, 0, stream>>>(srcp, dstp, row_ptr, fill, src_s, N_EDGES);

    const __hip_bfloat16* xc = xb16;
    for (int l = 0; l < 2; ++l) {
        gemmc_k<<<512, 256, 0, stream>>>(
            xc, cwb + (size_t)l * HIDDEN * HD,
            att_s + l * HD, att_d + l * HD, h8, a_src, a_dst, NTILES);
        if (l == 0)
            mp_k<__hip_bfloat16><<<NTILES, 256, 0, stream>>>(
                row_ptr, src_s, a_src, a_dst, h8, conv_b + l * HIDDEN,
                pwb + (size_t)l * HIDDEN * HIDDEN, xc, swb + (size_t)l * HIDDEN * HIDDEN,
                proj_b + l * HIDDEN, skip_b + l * HIDDEN, xb);
        else
            mp_k<float><<<NTILES, 256, 0, stream>>>(
                row_ptr, src_s, a_src, a_dst, h8, conv_b + l * HIDDEN,
                pwb + (size_t)l * HIDDEN * HIDDEN, xc, swb + (size_t)l * HIDDEN * HIDDEN,
                proj_b + l * HIDDEN, skip_b + l * HIDDEN, out);
        xc = xb;
    }
}

// Round 10
// 356.521 us; speedup vs baseline: 1.0834x; 1.0834x over previous
//
#include <hip/hip_runtime.h>
#include <hip/hip_bf16.h>
#include <stdint.h>

#define N_NODES 50000
#define N_EDGES 800000
#define HIDDEN  128
#define HEADS   4
#define HD      (HEADS*HIDDEN)   // 512
#define CAST_Q  (N_NODES*HIDDEN/4)   // 1,600,000 float4 quads of x
#define NTILES  (N_NODES/16)         // 3125 (exact)

typedef __attribute__((ext_vector_type(8))) short  short8;
typedef __attribute__((ext_vector_type(4))) float  floatx4;
typedef __attribute__((ext_vector_type(2))) float  floatx2;

static __device__ __forceinline__ unsigned short bf16_bits(float f) {
    __hip_bfloat16 h = __float2bfloat16(f);
    union { __hip_bfloat16 b; unsigned short s; } u; u.b = h; return u.s;
}

// leaky_relu(a, 0.2) == max(a, 0.2a); then fast exp
static __device__ __forceinline__ float lexp(float a) {
    return __expf(fmaxf(a, 0.2f * a));
}

// ---------------- fp8 e4m3 encode/decode (HW cvt when available) ----------------

#if __has_builtin(__builtin_amdgcn_cvt_pk_fp8_f32) && __has_builtin(__builtin_amdgcn_cvt_pk_f32_fp8)
#define FP8_HW 1
#else
#define FP8_HW 0
static __device__ __forceinline__ unsigned fp8_enc1(float f) {
    unsigned s = __float_as_uint(f) >> 31;
    float a = fabsf(f);
    if (a < 0.0009765625f) return s << 7;
    if (a > 448.f) a = 448.f;
    unsigned ub = __float_as_uint(a) + 0x00080000u;  // round at bit19
    int e = (int)((ub >> 23) & 255) - 120;           // biased-7 exponent
    unsigned m = (ub >> 20) & 7;
    if (e <= 0) {
        int mm = (int)(a * 512.f + 0.5f); if (mm > 7) mm = 7;
        return (s << 7) | (unsigned)mm;
    }
    if (e > 15) { e = 15; m = 7; }
    return (s << 7) | ((unsigned)e << 3) | m;
}
static __device__ __forceinline__ float fp8_dec1(unsigned b) {
    unsigned s = (b >> 7) & 1, e = (b >> 3) & 15, m = b & 7;
    if (e == 0) { float f = (float)m * 0.001953125f; return s ? -f : f; }
    return __uint_as_float((s << 31) | ((e + 120) << 23) | (m << 20));
}
#endif

static __device__ __forceinline__ unsigned fp8_pack4(float a, float b, float c, float d) {
#if FP8_HW
    int w = __builtin_amdgcn_cvt_pk_fp8_f32(a, b, 0, false);
    w     = __builtin_amdgcn_cvt_pk_fp8_f32(c, d, w, true);
    return (unsigned)w;
#else
    return fp8_enc1(a) | (fp8_enc1(b) << 8) | (fp8_enc1(c) << 16) | (fp8_enc1(d) << 24);
#endif
}

static __device__ __forceinline__ void accf8(float* acc, uint2 u, float wt) {
#if FP8_HW
    floatx2 f;
    f = __builtin_amdgcn_cvt_pk_f32_fp8((int)u.x, false); acc[0] += wt * f.x; acc[1] += wt * f.y;
    f = __builtin_amdgcn_cvt_pk_f32_fp8((int)u.x, true);  acc[2] += wt * f.x; acc[3] += wt * f.y;
    f = __builtin_amdgcn_cvt_pk_f32_fp8((int)u.y, false); acc[4] += wt * f.x; acc[5] += wt * f.y;
    f = __builtin_amdgcn_cvt_pk_f32_fp8((int)u.y, true);  acc[6] += wt * f.x; acc[7] += wt * f.y;
#else
    acc[0] += wt * fp8_dec1(u.x & 255);         acc[1] += wt * fp8_dec1((u.x >> 8) & 255);
    acc[2] += wt * fp8_dec1((u.x >> 16) & 255); acc[3] += wt * fp8_dec1(u.x >> 24);
    acc[4] += wt * fp8_dec1(u.y & 255);         acc[5] += wt * fp8_dec1((u.y >> 8) & 255);
    acc[6] += wt * fp8_dec1((u.y >> 16) & 255); acc[7] += wt * fp8_dec1(u.y >> 24);
#endif
}

// ---------------- prep: x cast + weight swizzle + dst histogram, one launch ----------------
// ranges: [0, CAST_Q) cast; [CAST_Q, CAST_Q+196608) swizzle; then N_EDGES histogram.
// proj_w rows PERMUTED (kr -> (kr&7)*16 + (kr>>3)) to compensate rc's [r][ntl] layout.

__global__ __launch_bounds__(256) void prep_k(
        const float* __restrict__ x, unsigned short* __restrict__ xb16,
        const float* __restrict__ conv_w, const float* __restrict__ proj_w,
        const float* __restrict__ skip_w,
        unsigned short* __restrict__ cwb, unsigned short* __restrict__ pwb,
        unsigned short* __restrict__ swb,
        const int* __restrict__ dst, int* __restrict__ cnt) {
    int i = blockIdx.x * 256 + threadIdx.x;
    if (i < CAST_Q) {
        float4 v = ((const float4*)x)[i];
        uint2 p;
        p.x = (unsigned)bf16_bits(v.x) | ((unsigned)bf16_bits(v.y) << 16);
        p.y = (unsigned)bf16_bits(v.z) | ((unsigned)bf16_bits(v.w) << 16);
        ((uint2*)xb16)[i] = p;
        return;
    }
    int o = i - CAST_Q;
    if (o >= 196608) {
        int e = o - 196608;
        if (e < N_EDGES) atomicAdd(&cnt[dst[e]], 1);
        return;
    }
    const float* B; unsigned short* D; int off, N; bool perm = false;
    if (o < 131072)      { B = conv_w + (o >> 16) * 65536; D = cwb + (o >> 16) * 65536; off = o & 65535; N = 512; }
    else if (o < 163840) { int t = o - 131072; B = proj_w + (t >> 14) * 16384; D = pwb + (t >> 14) * 16384; off = t & 16383; N = 128; perm = true; }
    else                 { int t = o - 163840; B = skip_w + (t >> 14) * 16384; D = swb + (t >> 14) * 16384; off = t & 16383; N = 128; }
    int j = off & 7, r = (off >> 3) & 15, q = (off >> 7) & 3;
    int rest = off >> 9, ntn = N >> 4;
    int nt = rest % ntn, kc = rest / ntn;
    int kr = kc * 32 + q * 8 + j;
    int row = perm ? ((kr & 7) * 16 + (kr >> 3)) : kr;
    D[off] = bf16_bits(B[(size_t)row * N + nt * 16 + r]);
}

// ---------------- CSR build ----------------

__global__ __launch_bounds__(1024) void scan1_k(const int* __restrict__ cnt,
                                                int* __restrict__ row_ptr,
                                                int* __restrict__ bsum, int n) {
    __shared__ int buf[1024];
    int t = threadIdx.x, i = blockIdx.x * 1024 + t;
    int v = (i < n) ? cnt[i] : 0;
    buf[t] = v;
    __syncthreads();
    for (int off = 1; off < 1024; off <<= 1) {
        int xv = (t >= off) ? buf[t - off] : 0;
        __syncthreads();
        buf[t] += xv;
        __syncthreads();
    }
    if (i < n) row_ptr[i] = buf[t] - v;
    if (t == 1023) bsum[blockIdx.x] = buf[1023];
}

__global__ void scan2_k(int* __restrict__ bsum, int nb) {
    if (threadIdx.x == 0) {
        int acc = 0;
        for (int i = 0; i < nb; ++i) { int v = bsum[i]; bsum[i] = acc; acc += v; }
    }
}

__global__ __launch_bounds__(1024) void scan3_k(int* __restrict__ row_ptr,
                                                const int* __restrict__ bsum, int n, int E) {
    int i = blockIdx.x * 1024 + threadIdx.x;
    if (i < n) row_ptr[i] += bsum[blockIdx.x];
    if (i == 0) row_ptr[n] = E;
}

__global__ __launch_bounds__(256) void scatter_k(const int* __restrict__ src,
                                                 const int* __restrict__ dst,
                                                 const int* __restrict__ row_ptr,
                                                 int* __restrict__ fill,
                                                 int* __restrict__ src_sorted, int E) {
    int e = blockIdx.x * 256 + threadIdx.x;
    if (e >= E) return;
    int d = dst[e];
    int p = row_ptr[d] + atomicAdd(&fill[d], 1);
    src_sorted[p] = src[e];
}

// ---------------- conv GEMM: h8 = fp8(A@conv_w), B-in-regs, A prefetch pipeline ----------------
// h8 row layout (bytes): [head][r][ntl]; natural channel ntl*16+r at byte r*8+ntl of head slice.

__global__ __launch_bounds__(256, 2) void gemmc_k(
        const __hip_bfloat16* __restrict__ A,      // M x 128 bf16 (natural)
        const unsigned short* __restrict__ Bs,     // swizzled 128x512
        const float* __restrict__ att_s, const float* __restrict__ att_d,
        unsigned char* __restrict__ h8,
        float* __restrict__ a_src, float* __restrict__ a_dst, int mtiles) {
    int head = threadIdx.x >> 6;
    int lane = threadIdx.x & 63;
    int r = lane & 15, q = lane >> 4;

    short8 Bf[4][8];
#pragma unroll
    for (int kc = 0; kc < 4; ++kc)
#pragma unroll
        for (int ntl = 0; ntl < 8; ++ntl)
            Bf[kc][ntl] = *(const short8*)((const short*)Bs +
                (((size_t)(kc * 32 + head * 8 + ntl) * 4 + q) * 128 + r * 8));

    float as_r[8], ad_r[8];
#pragma unroll
    for (int ntl = 0; ntl < 8; ++ntl) {
        as_r[ntl] = att_s[head * HIDDEN + ntl * 16 + r];
        ad_r[ntl] = att_d[head * HIDDEN + ntl * 16 + r];
    }

    const int stride = gridDim.x;
    int mt = blockIdx.x;
    short8 av[4];
    if (mt < mtiles) {
        const short* Ab = (const short*)A + (size_t)(mt * 16 + r) * HIDDEN + q * 8;
#pragma unroll
        for (int kc = 0; kc < 4; ++kc) av[kc] = *(const short8*)(Ab + kc * 32);
    }
    while (mt < mtiles) {
        int nmt = mt + stride;
        short8 avn[4];
        if (nmt < mtiles) {
            const short* Ab = (const short*)A + (size_t)(nmt * 16 + r) * HIDDEN + q * 8;
#pragma unroll
            for (int kc = 0; kc < 4; ++kc) avn[kc] = *(const short8*)(Ab + kc * 32);
        }
        int m0 = mt * 16;
        floatx4 acc[8];
#pragma unroll
        for (int i = 0; i < 8; ++i) acc[i] = (floatx4){0.f, 0.f, 0.f, 0.f};
#pragma unroll
        for (int kc = 0; kc < 4; ++kc)
#pragma unroll
            for (int ntl = 0; ntl < 8; ++ntl)
                acc[ntl] = __builtin_amdgcn_mfma_f32_16x16x32_bf16(av[kc], Bf[kc][ntl], acc[ntl], 0, 0, 0);

        // store h8: row q*4+i, 8 B per row per lane
#pragma unroll
        for (int i = 0; i < 4; ++i) {
            uint2 o;
            o.x = fp8_pack4(acc[0][i], acc[1][i], acc[2][i], acc[3][i]);
            o.y = fp8_pack4(acc[4][i], acc[5][i], acc[6][i], acc[7][i]);
            *(uint2*)(h8 + (size_t)(m0 + q * 4 + i) * HD + head * HIDDEN + r * 8) = o;
        }
        // fused alpha (fp32 accumulators — full precision)
        float sA[4] = {0, 0, 0, 0}, sD[4] = {0, 0, 0, 0};
#pragma unroll
        for (int ntl = 0; ntl < 8; ++ntl)
#pragma unroll
            for (int i = 0; i < 4; ++i) {
                sA[i] += acc[ntl][i] * as_r[ntl];
                sD[i] += acc[ntl][i] * ad_r[ntl];
            }
#pragma unroll
        for (int d = 1; d < 16; d <<= 1)
#pragma unroll
            for (int i = 0; i < 4; ++i) {
                sA[i] += __shfl_xor(sA[i], d);
                sD[i] += __shfl_xor(sD[i], d);
            }
        if (r == 0)
#pragma unroll
            for (int i = 0; i < 4; ++i) {
                int row = m0 + q * 4 + i;
                a_src[row * HEADS + head] = sA[i];
                a_dst[row * HEADS + head] = sD[i];
            }
        mt = nmt;
#pragma unroll
        for (int kc = 0; kc < 4; ++kc) av[kc] = avn[kc];
    }
}

// ---------------- proj+skip dual GEMM: B-in-regs, A/A2 prefetch pipeline ----------------

template <typename OutT>
__global__ __launch_bounds__(256, 2) void gemmp_k(
        const __hip_bfloat16* __restrict__ A,  const unsigned short* __restrict__ Bs,
        const __hip_bfloat16* __restrict__ A2, const unsigned short* __restrict__ Bs2,
        const float* __restrict__ b1, const float* __restrict__ b2,
        OutT* __restrict__ D, int mtiles) {
    int wave = threadIdx.x >> 6;
    int lane = threadIdx.x & 63;
    int r = lane & 15, q = lane >> 4;
    int nh = wave & 1;

    short8 Bf[4][4], Bf2[4][4];
#pragma unroll
    for (int kc = 0; kc < 4; ++kc)
#pragma unroll
        for (int ntl = 0; ntl < 4; ++ntl) {
            size_t off = (((size_t)(kc * 8 + nh * 4 + ntl) * 4 + q) * 128 + r * 8);
            Bf[kc][ntl]  = *(const short8*)((const short*)Bs  + off);
            Bf2[kc][ntl] = *(const short8*)((const short*)Bs2 + off);
        }
    float bias[4];
#pragma unroll
    for (int ntl = 0; ntl < 4; ++ntl) {
        int col = nh * 64 + ntl * 16 + r;
        bias[ntl] = b1[col] + b2[col];
    }

    const int stride = gridDim.x * 2;
    int mt = blockIdx.x * 2 + (wave >> 1);
    short8 av[4], av2[4];
    if (mt < mtiles) {
        const short* Ab  = (const short*)A  + (size_t)(mt * 16 + r) * HIDDEN + q * 8;
        const short* Ab2 = (const short*)A2 + (size_t)(mt * 16 + r) * HIDDEN + q * 8;
#pragma unroll
        for (int kc = 0; kc < 4; ++kc) {
            av[kc]  = *(const short8*)(Ab  + kc * 32);
            av2[kc] = *(const short8*)(Ab2 + kc * 32);
        }
    }
    while (mt < mtiles) {
        int nmt = mt + stride;
        short8 avn[4], avn2[4];
        if (nmt < mtiles) {
            const short* Ab  = (const short*)A  + (size_t)(nmt * 16 + r) * HIDDEN + q * 8;
            const short* Ab2 = (const short*)A2 + (size_t)(nmt * 16 + r) * HIDDEN + q * 8;
#pragma unroll
            for (int kc = 0; kc < 4; ++kc) {
                avn[kc]  = *(const short8*)(Ab  + kc * 32);
                avn2[kc] = *(const short8*)(Ab2 + kc * 32);
            }
        }
        int m0 = mt * 16;
        floatx4 acc[4];
#pragma unroll
        for (int i = 0; i < 4; ++i) acc[i] = (floatx4){0.f, 0.f, 0.f, 0.f};
#pragma unroll
        for (int kc = 0; kc < 4; ++kc)
#pragma unroll
            for (int ntl = 0; ntl < 4; ++ntl) {
                acc[ntl] = __builtin_amdgcn_mfma_f32_16x16x32_bf16(av[kc],  Bf[kc][ntl],  acc[ntl], 0, 0, 0);
                acc[ntl] = __builtin_amdgcn_mfma_f32_16x16x32_bf16(av2[kc], Bf2[kc][ntl], acc[ntl], 0, 0, 0);
            }
#pragma unroll
        for (int ntl = 0; ntl < 4; ++ntl) {
            int col = nh * 64 + ntl * 16 + r;
#pragma unroll
            for (int i = 0; i < 4; ++i) {
                int row = m0 + q * 4 + i;
                float v = acc[ntl][i] + bias[ntl];
                if constexpr (sizeof(OutT) == 4)
                    ((float*)D)[(size_t)row * HIDDEN + col] = v;
                else
                    ((__hip_bfloat16*)D)[(size_t)row * HIDDEN + col] = __float2bfloat16(v);
            }
        }
        mt = nmt;
#pragma unroll
        for (int kc = 0; kc < 4; ++kc) { av[kc] = avn[kc]; av2[kc] = avn2[kc]; }
    }
}

// ---------------- fused softmax + aggregation: one wave per node, fp8 h (R8-proven) ----------------

__global__ __launch_bounds__(256) void msg_k(const int* __restrict__ row_ptr,
                                             const int* __restrict__ src_sorted,
                                             const float* __restrict__ a_src,
                                             const float* __restrict__ a_dst,
                                             const unsigned char* __restrict__ h8,
                                             const float* __restrict__ conv_b,
                                             __hip_bfloat16* __restrict__ rc) {
    int wave = threadIdx.x >> 6;
    int lane = threadIdx.x & 63;
    int n = blockIdx.x * 4 + wave;
    if (n >= N_NODES) return;
    int head = lane >> 4;
    float adn = a_dst[n * HEADS + head];
    int beg = row_ptr[n], end = row_ptr[n + 1];
    const uint2* hq = (const uint2*)h8;

    float acc[8] = {0.f, 0.f, 0.f, 0.f, 0.f, 0.f, 0.f, 0.f};
    float esum = 0.f;
    for (int base = beg; base < end; base += 32) {
        int m = min(32, end - base);
        int sv = (lane < m) ? src_sorted[base + lane] : 0;
        int j = 0;
        for (; j + 4 <= m; j += 4) {
            int s0 = __shfl(sv, j),     s1 = __shfl(sv, j + 1);
            int s2 = __shfl(sv, j + 2), s3 = __shfl(sv, j + 3);
            uint2 u0 = hq[(size_t)s0 * 64 + lane];
            uint2 u1 = hq[(size_t)s1 * 64 + lane];
            uint2 u2 = hq[(size_t)s2 * 64 + lane];
            uint2 u3 = hq[(size_t)s3 * 64 + lane];
            float e0 = lexp(a_src[s0 * 4 + head] + adn);
            float e1 = lexp(a_src[s1 * 4 + head] + adn);
            float e2 = lexp(a_src[s2 * 4 + head] + adn);
            float e3 = lexp(a_src[s3 * 4 + head] + adn);
            accf8(acc, u0, e0);
            accf8(acc, u1, e1);
            accf8(acc, u2, e2);
            accf8(acc, u3, e3);
            esum += (e0 + e1) + (e2 + e3);
        }
        for (; j < m; ++j) {
            int s0 = __shfl(sv, j);
            uint2 u0 = hq[(size_t)s0 * 64 + lane];
            float e0 = lexp(a_src[s0 * 4 + head] + adn);
            accf8(acc, u0, e0);
            esum += e0;
        }
    }
    float rinv = 1.f / (esum + 1e-16f);
#pragma unroll
    for (int k = 0; k < 8; ++k) acc[k] *= rinv;
#pragma unroll
    for (int k = 0; k < 8; ++k) {
        acc[k] += __shfl_xor(acc[k], 16);
        acc[k] += __shfl_xor(acc[k], 32);
    }
    if (lane < 16) {
        // lane holds natural channels {k*16+lane}; rc written permuted [r][ntl]
        union { uint4 v; unsigned short us[8]; } o;
#pragma unroll
        for (int k = 0; k < 8; ++k) {
            float mres = 0.25f * acc[k] + conv_b[k * 16 + lane];
            o.us[k] = bf16_bits(mres > 0.f ? mres : 0.f);
        }
        ((uint4*)rc)[(size_t)n * 16 + lane] = o.v;
    }
}

// ---------------- launcher ----------------

extern "C" void kernel_launch(void* const* d_in, const int* in_sizes, int n_in,
                              void* d_out, int out_size, void* d_ws, size_t ws_size,
                              hipStream_t stream) {
    const float* x      = (const float*)d_in[0];
    const int*   ei     = (const int*)d_in[1];
    const float* conv_w = (const float*)d_in[2];
    const float* att_s  = (const float*)d_in[3];
    const float* att_d  = (const float*)d_in[4];
    const float* conv_b = (const float*)d_in[5];
    const float* proj_w = (const float*)d_in[6];
    const float* proj_b = (const float*)d_in[7];
    const float* skip_w = (const float*)d_in[8];
    const float* skip_b = (const float*)d_in[9];
    float* out = (float*)d_out;

    char* ws = (char*)d_ws;
    size_t o = 0;
    auto alloc = [&](size_t b) { size_t c = o; o += (b + 255) & ~(size_t)255; return c; };
    __hip_bfloat16* xb16 = (__hip_bfloat16*)(ws + alloc((size_t)N_NODES * HIDDEN * 2));
    unsigned short* cwb  = (unsigned short*)(ws + alloc((size_t)2 * HIDDEN * HD * 2));
    unsigned short* pwb  = (unsigned short*)(ws + alloc((size_t)2 * HIDDEN * HIDDEN * 2));
    unsigned short* swb  = (unsigned short*)(ws + alloc((size_t)2 * HIDDEN * HIDDEN * 2));
    unsigned char* h8    = (unsigned char*)(ws + alloc((size_t)N_NODES * HD));
    float* a_src         = (float*)(ws + alloc((size_t)N_NODES * HEADS * 4));
    float* a_dst         = (float*)(ws + alloc((size_t)N_NODES * HEADS * 4));
    int* row_ptr         = (int*)(ws + alloc((size_t)(N_NODES + 1) * 4));
    int* cntfill         = (int*)(ws + alloc((size_t)2 * N_NODES * 4));
    int* cnt  = cntfill;
    int* fill = cntfill + N_NODES;
    int* src_s           = (int*)(ws + alloc((size_t)N_EDGES * 4));
    __hip_bfloat16* rc   = (__hip_bfloat16*)(ws + alloc((size_t)N_NODES * HIDDEN * 2));
    __hip_bfloat16* xb   = (__hip_bfloat16*)(ws + alloc((size_t)N_NODES * HIDDEN * 2));
    int* bsum            = (int*)(ws + alloc(64 * 4));

    const int* srcp = ei;
    const int* dstp = ei + N_EDGES;

    (void)hipMemsetAsync(cntfill, 0, (size_t)2 * N_NODES * 4, stream);

    prep_k<<<(CAST_Q + 196608 + N_EDGES + 255) / 256, 256, 0, stream>>>(
        x, (unsigned short*)xb16, conv_w, proj_w, skip_w, cwb, pwb, swb, dstp, cnt);

    const int nb = (N_NODES + 1023) / 1024;  // 49
    scan1_k<<<nb, 1024, 0, stream>>>(cnt, row_ptr, bsum, N_NODES);
    scan2_k<<<1, 64, 0, stream>>>(bsum, nb);
    scan3_k<<<nb, 1024, 0, stream>>>(row_ptr, bsum, N_NODES, N_EDGES);
    scatter_k<<<(N_EDGES + 255) / 256, 256, 0, stream>>>(srcp, dstp, row_ptr, fill, src_s, N_EDGES);

    const __hip_bfloat16* xc = xb16;
    for (int l = 0; l < 2; ++l) {
        gemmc_k<<<512, 256, 0, stream>>>(
            xc, cwb + (size_t)l * HIDDEN * HD,
            att_s + l * HD, att_d + l * HD, h8, a_src, a_dst, NTILES);
        msg_k<<<(N_NODES + 3) / 4, 256, 0, stream>>>(
            row_ptr, src_s, a_src, a_dst, h8, conv_b + l * HIDDEN, rc);
        if (l == 0)
            gemmp_k<__hip_bfloat16><<<512, 256, 0, stream>>>(
                rc, pwb + (size_t)l * HIDDEN * HIDDEN,
                xc, swb + (size_t)l * HIDDEN * HIDDEN,
                proj_b + l * HIDDEN, skip_b + l * HIDDEN, xb, NTILES);
        else
            gemmp_k<float><<<512, 256, 0, stream>>>(
                rc, pwb + (size_t)l * HIDDEN * HIDDEN,
                xc, swb + (size_t)l * HIDDEN * HIDDEN,
                proj_b + l * HIDDEN, skip_b + l * HIDDEN, out, NTILES);
        xc = xb;
    }
}

// Round 11
// 355.323 us; speedup vs baseline: 1.0871x; 1.0034x over previous
//
#include <hip/hip_runtime.h>
#include <hip/hip_bf16.h>
#include <stdint.h>

#define N_NODES 50000
#define N_EDGES 800000
#define HIDDEN  128
#define HEADS   4
#define HD      (HEADS*HIDDEN)   // 512
#define CAST_Q  (N_NODES*HIDDEN/4)   // 1,600,000 float4 quads of x
#define NTILES  (N_NODES/16)         // 3125 (exact)

typedef __attribute__((ext_vector_type(8))) short  short8;
typedef __attribute__((ext_vector_type(4))) float  floatx4;
typedef __attribute__((ext_vector_type(2))) float  floatx2;

static __device__ __forceinline__ unsigned short bf16_bits(float f) {
    __hip_bfloat16 h = __float2bfloat16(f);
    union { __hip_bfloat16 b; unsigned short s; } u; u.b = h; return u.s;
}

// leaky_relu(a, 0.2) == max(a, 0.2a); then fast exp
static __device__ __forceinline__ float lexp(float a) {
    return __expf(fmaxf(a, 0.2f * a));
}

// ---------------- fp8 e4m3 encode/decode (HW cvt when available) ----------------

#if __has_builtin(__builtin_amdgcn_cvt_pk_fp8_f32) && __has_builtin(__builtin_amdgcn_cvt_pk_f32_fp8)
#define FP8_HW 1
#else
#define FP8_HW 0
static __device__ __forceinline__ unsigned fp8_enc1(float f) {
    unsigned s = __float_as_uint(f) >> 31;
    float a = fabsf(f);
    if (a < 0.0009765625f) return s << 7;
    if (a > 448.f) a = 448.f;
    unsigned ub = __float_as_uint(a) + 0x00080000u;  // round at bit19
    int e = (int)((ub >> 23) & 255) - 120;           // biased-7 exponent
    unsigned m = (ub >> 20) & 7;
    if (e <= 0) {
        int mm = (int)(a * 512.f + 0.5f); if (mm > 7) mm = 7;
        return (s << 7) | (unsigned)mm;
    }
    if (e > 15) { e = 15; m = 7; }
    return (s << 7) | ((unsigned)e << 3) | m;
}
static __device__ __forceinline__ floatx2 fp8_dec_pk(unsigned b2) {
    // decode two fp8 bytes (lo, hi of b2[15:0])
    floatx2 r;
    unsigned b = b2 & 255;
    {
        unsigned s = (b >> 7) & 1, e = (b >> 3) & 15, m = b & 7;
        r.x = (e == 0) ? ((s ? -1.f : 1.f) * (float)m * 0.001953125f)
                       : __uint_as_float((s << 31) | ((e + 120) << 23) | (m << 20));
    }
    b = (b2 >> 8) & 255;
    {
        unsigned s = (b >> 7) & 1, e = (b >> 3) & 15, m = b & 7;
        r.y = (e == 0) ? ((s ? -1.f : 1.f) * (float)m * 0.001953125f)
                       : __uint_as_float((s << 31) | ((e + 120) << 23) | (m << 20));
    }
    return r;
}
#endif

static __device__ __forceinline__ unsigned fp8_pack4(float a, float b, float c, float d) {
#if FP8_HW
    int w = __builtin_amdgcn_cvt_pk_fp8_f32(a, b, 0, false);
    w     = __builtin_amdgcn_cvt_pk_fp8_f32(c, d, w, true);
    return (unsigned)w;
#else
    return fp8_enc1(a) | (fp8_enc1(b) << 8) | (fp8_enc1(c) << 16) | (fp8_enc1(d) << 24);
#endif
}

// packed accumulate: acc2[0..3] += w * decode8(u)   (floatx2 math -> v_pk_fma_f32)
static __device__ __forceinline__ void accf8p(floatx2* acc2, uint2 u, float wt) {
    floatx2 wv = {wt, wt};
#if FP8_HW
    acc2[0] += wv * __builtin_amdgcn_cvt_pk_f32_fp8((int)u.x, false);
    acc2[1] += wv * __builtin_amdgcn_cvt_pk_f32_fp8((int)u.x, true);
    acc2[2] += wv * __builtin_amdgcn_cvt_pk_f32_fp8((int)u.y, false);
    acc2[3] += wv * __builtin_amdgcn_cvt_pk_f32_fp8((int)u.y, true);
#else
    acc2[0] += wv * fp8_dec_pk(u.x);
    acc2[1] += wv * fp8_dec_pk(u.x >> 16);
    acc2[2] += wv * fp8_dec_pk(u.y);
    acc2[3] += wv * fp8_dec_pk(u.y >> 16);
#endif
}

// ---------------- prep: x cast + weight swizzle + dst histogram, one launch ----------------
// ranges: [0, CAST_Q) cast; [CAST_Q, CAST_Q+196608) swizzle; then N_EDGES histogram.
// proj_w rows PERMUTED (kr -> (kr&7)*16 + (kr>>3)) to compensate rc's [r][ntl] layout.

__global__ __launch_bounds__(256) void prep_k(
        const float* __restrict__ x, unsigned short* __restrict__ xb16,
        const float* __restrict__ conv_w, const float* __restrict__ proj_w,
        const float* __restrict__ skip_w,
        unsigned short* __restrict__ cwb, unsigned short* __restrict__ pwb,
        unsigned short* __restrict__ swb,
        const int* __restrict__ dst, int* __restrict__ cnt) {
    int i = blockIdx.x * 256 + threadIdx.x;
    if (i < CAST_Q) {
        float4 v = ((const float4*)x)[i];
        uint2 p;
        p.x = (unsigned)bf16_bits(v.x) | ((unsigned)bf16_bits(v.y) << 16);
        p.y = (unsigned)bf16_bits(v.z) | ((unsigned)bf16_bits(v.w) << 16);
        ((uint2*)xb16)[i] = p;
        return;
    }
    int o = i - CAST_Q;
    if (o >= 196608) {
        int e = o - 196608;
        if (e < N_EDGES) atomicAdd(&cnt[dst[e]], 1);
        return;
    }
    const float* B; unsigned short* D; int off, N; bool perm = false;
    if (o < 131072)      { B = conv_w + (o >> 16) * 65536; D = cwb + (o >> 16) * 65536; off = o & 65535; N = 512; }
    else if (o < 163840) { int t = o - 131072; B = proj_w + (t >> 14) * 16384; D = pwb + (t >> 14) * 16384; off = t & 16383; N = 128; perm = true; }
    else                 { int t = o - 163840; B = skip_w + (t >> 14) * 16384; D = swb + (t >> 14) * 16384; off = t & 16383; N = 128; }
    int j = off & 7, r = (off >> 3) & 15, q = (off >> 7) & 3;
    int rest = off >> 9, ntn = N >> 4;
    int nt = rest % ntn, kc = rest / ntn;
    int kr = kc * 32 + q * 8 + j;
    int row = perm ? ((kr & 7) * 16 + (kr >> 3)) : kr;
    D[off] = bf16_bits(B[(size_t)row * N + nt * 16 + r]);
}

// ---------------- CSR build ----------------
// scan1: cnt[i] <- block-local exclusive scan; bsum[b] <- block total.

__global__ __launch_bounds__(1024) void scan1_k(int* __restrict__ cnt,
                                                int* __restrict__ bsum, int n) {
    __shared__ int buf[1024];
    int t = threadIdx.x, i = blockIdx.x * 1024 + t;
    int v = (i < n) ? cnt[i] : 0;
    buf[t] = v;
    __syncthreads();
    for (int off = 1; off < 1024; off <<= 1) {
        int xv = (t >= off) ? buf[t - off] : 0;
        __syncthreads();
        buf[t] += xv;
        __syncthreads();
    }
    if (i < n) cnt[i] = buf[t] - v;              // local exclusive
    if (t == 1023) bsum[blockIdx.x] = buf[1023];
}

__global__ void scan2_k(int* __restrict__ bsum, int nb) {
    if (threadIdx.x == 0) {
        int acc = 0;
        for (int i = 0; i < nb; ++i) { int v = bsum[i]; bsum[i] = acc; acc += v; }
    }
}

// merged scan3 + scatter: scatter computes absolute position from cnt+bsum (read-only);
// finalize threads write row_ptr (disjoint array -> no race).
__global__ __launch_bounds__(256) void scansc_k(const int* __restrict__ src,
                                                const int* __restrict__ dst,
                                                const int* __restrict__ cnt,
                                                const int* __restrict__ bsum,
                                                int* __restrict__ fill,
                                                int* __restrict__ src_sorted,
                                                int* __restrict__ row_ptr) {
    int i = blockIdx.x * 256 + threadIdx.x;
    if (i < N_EDGES) {
        int d = dst[i];
        int p = cnt[d] + bsum[d >> 10] + atomicAdd(&fill[d], 1);
        src_sorted[p] = src[i];
        return;
    }
    int j = i - N_EDGES;
    if (j < N_NODES) {
        row_ptr[j] = cnt[j] + bsum[j >> 10];
        if (j == 0) row_ptr[N_NODES] = N_EDGES;
    }
}

// ---------------- conv GEMM: h8 = fp8(A@conv_w), B-in-regs, A prefetch pipeline ----------------
// h8 row layout (bytes): [head][r][ntl]; natural channel ntl*16+r at byte r*8+ntl of head slice.

__global__ __launch_bounds__(256, 2) void gemmc_k(
        const __hip_bfloat16* __restrict__ A,      // M x 128 bf16 (natural)
        const unsigned short* __restrict__ Bs,     // swizzled 128x512
        const float* __restrict__ att_s, const float* __restrict__ att_d,
        unsigned char* __restrict__ h8,
        float* __restrict__ a_src, float* __restrict__ a_dst, int mtiles) {
    int head = threadIdx.x >> 6;
    int lane = threadIdx.x & 63;
    int r = lane & 15, q = lane >> 4;

    short8 Bf[4][8];
#pragma unroll
    for (int kc = 0; kc < 4; ++kc)
#pragma unroll
        for (int ntl = 0; ntl < 8; ++ntl)
            Bf[kc][ntl] = *(const short8*)((const short*)Bs +
                (((size_t)(kc * 32 + head * 8 + ntl) * 4 + q) * 128 + r * 8));

    float as_r[8], ad_r[8];
#pragma unroll
    for (int ntl = 0; ntl < 8; ++ntl) {
        as_r[ntl] = att_s[head * HIDDEN + ntl * 16 + r];
        ad_r[ntl] = att_d[head * HIDDEN + ntl * 16 + r];
    }

    const int stride = gridDim.x;
    int mt = blockIdx.x;
    short8 av[4];
    if (mt < mtiles) {
        const short* Ab = (const short*)A + (size_t)(mt * 16 + r) * HIDDEN + q * 8;
#pragma unroll
        for (int kc = 0; kc < 4; ++kc) av[kc] = *(const short8*)(Ab + kc * 32);
    }
    while (mt < mtiles) {
        int nmt = mt + stride;
        short8 avn[4];
        if (nmt < mtiles) {
            const short* Ab = (const short*)A + (size_t)(nmt * 16 + r) * HIDDEN + q * 8;
#pragma unroll
            for (int kc = 0; kc < 4; ++kc) avn[kc] = *(const short8*)(Ab + kc * 32);
        }
        int m0 = mt * 16;
        floatx4 acc[8];
#pragma unroll
        for (int i = 0; i < 8; ++i) acc[i] = (floatx4){0.f, 0.f, 0.f, 0.f};
#pragma unroll
        for (int kc = 0; kc < 4; ++kc)
#pragma unroll
            for (int ntl = 0; ntl < 8; ++ntl)
                acc[ntl] = __builtin_amdgcn_mfma_f32_16x16x32_bf16(av[kc], Bf[kc][ntl], acc[ntl], 0, 0, 0);

        // store h8: row q*4+i, 8 B per row per lane
#pragma unroll
        for (int i = 0; i < 4; ++i) {
            uint2 o;
            o.x = fp8_pack4(acc[0][i], acc[1][i], acc[2][i], acc[3][i]);
            o.y = fp8_pack4(acc[4][i], acc[5][i], acc[6][i], acc[7][i]);
            *(uint2*)(h8 + (size_t)(m0 + q * 4 + i) * HD + head * HIDDEN + r * 8) = o;
        }
        // fused alpha (fp32 accumulators — full precision)
        float sA[4] = {0, 0, 0, 0}, sD[4] = {0, 0, 0, 0};
#pragma unroll
        for (int ntl = 0; ntl < 8; ++ntl)
#pragma unroll
            for (int i = 0; i < 4; ++i) {
                sA[i] += acc[ntl][i] * as_r[ntl];
                sD[i] += acc[ntl][i] * ad_r[ntl];
            }
#pragma unroll
        for (int d = 1; d < 16; d <<= 1)
#pragma unroll
            for (int i = 0; i < 4; ++i) {
                sA[i] += __shfl_xor(sA[i], d);
                sD[i] += __shfl_xor(sD[i], d);
            }
        if (r == 0)
#pragma unroll
            for (int i = 0; i < 4; ++i) {
                int row = m0 + q * 4 + i;
                a_src[row * HEADS + head] = sA[i];
                a_dst[row * HEADS + head] = sD[i];
            }
        mt = nmt;
#pragma unroll
        for (int kc = 0; kc < 4; ++kc) av[kc] = avn[kc];
    }
}

// ---------------- proj+skip dual GEMM: B-in-regs, A/A2 prefetch pipeline ----------------

template <typename OutT>
__global__ __launch_bounds__(256, 2) void gemmp_k(
        const __hip_bfloat16* __restrict__ A,  const unsigned short* __restrict__ Bs,
        const __hip_bfloat16* __restrict__ A2, const unsigned short* __restrict__ Bs2,
        const float* __restrict__ b1, const float* __restrict__ b2,
        OutT* __restrict__ D, int mtiles) {
    int wave = threadIdx.x >> 6;
    int lane = threadIdx.x & 63;
    int r = lane & 15, q = lane >> 4;
    int nh = wave & 1;

    short8 Bf[4][4], Bf2[4][4];
#pragma unroll
    for (int kc = 0; kc < 4; ++kc)
#pragma unroll
        for (int ntl = 0; ntl < 4; ++ntl) {
            size_t off = (((size_t)(kc * 8 + nh * 4 + ntl) * 4 + q) * 128 + r * 8);
            Bf[kc][ntl]  = *(const short8*)((const short*)Bs  + off);
            Bf2[kc][ntl] = *(const short8*)((const short*)Bs2 + off);
        }
    float bias[4];
#pragma unroll
    for (int ntl = 0; ntl < 4; ++ntl) {
        int col = nh * 64 + ntl * 16 + r;
        bias[ntl] = b1[col] + b2[col];
    }

    const int stride = gridDim.x * 2;
    int mt = blockIdx.x * 2 + (wave >> 1);
    short8 av[4], av2[4];
    if (mt < mtiles) {
        const short* Ab  = (const short*)A  + (size_t)(mt * 16 + r) * HIDDEN + q * 8;
        const short* Ab2 = (const short*)A2 + (size_t)(mt * 16 + r) * HIDDEN + q * 8;
#pragma unroll
        for (int kc = 0; kc < 4; ++kc) {
            av[kc]  = *(const short8*)(Ab  + kc * 32);
            av2[kc] = *(const short8*)(Ab2 + kc * 32);
        }
    }
    while (mt < mtiles) {
        int nmt = mt + stride;
        short8 avn[4], avn2[4];
        if (nmt < mtiles) {
            const short* Ab  = (const short*)A  + (size_t)(nmt * 16 + r) * HIDDEN + q * 8;
            const short* Ab2 = (const short*)A2 + (size_t)(nmt * 16 + r) * HIDDEN + q * 8;
#pragma unroll
            for (int kc = 0; kc < 4; ++kc) {
                avn[kc]  = *(const short8*)(Ab  + kc * 32);
                avn2[kc] = *(const short8*)(Ab2 + kc * 32);
            }
        }
        int m0 = mt * 16;
        floatx4 acc[4];
#pragma unroll
        for (int i = 0; i < 4; ++i) acc[i] = (floatx4){0.f, 0.f, 0.f, 0.f};
#pragma unroll
        for (int kc = 0; kc < 4; ++kc)
#pragma unroll
            for (int ntl = 0; ntl < 4; ++ntl) {
                acc[ntl] = __builtin_amdgcn_mfma_f32_16x16x32_bf16(av[kc],  Bf[kc][ntl],  acc[ntl], 0, 0, 0);
                acc[ntl] = __builtin_amdgcn_mfma_f32_16x16x32_bf16(av2[kc], Bf2[kc][ntl], acc[ntl], 0, 0, 0);
            }
#pragma unroll
        for (int ntl = 0; ntl < 4; ++ntl) {
            int col = nh * 64 + ntl * 16 + r;
#pragma unroll
            for (int i = 0; i < 4; ++i) {
                int row = m0 + q * 4 + i;
                float v = acc[ntl][i] + bias[ntl];
                if constexpr (sizeof(OutT) == 4)
                    ((float*)D)[(size_t)row * HIDDEN + col] = v;
                else
                    ((__hip_bfloat16*)D)[(size_t)row * HIDDEN + col] = __float2bfloat16(v);
            }
        }
        mt = nmt;
#pragma unroll
        for (int kc = 0; kc < 4; ++kc) { av[kc] = avn[kc]; av2[kc] = avn2[kc]; }
    }
}

// ---------------- fused softmax + aggregation: one wave per node, fp8 h, packed FMA ----------------

__global__ __launch_bounds__(256) void msg_k(const int* __restrict__ row_ptr,
                                             const int* __restrict__ src_sorted,
                                             const float* __restrict__ a_src,
                                             const float* __restrict__ a_dst,
                                             const unsigned char* __restrict__ h8,
                                             const float* __restrict__ conv_b,
                                             __hip_bfloat16* __restrict__ rc) {
    int wave = threadIdx.x >> 6;
    int lane = threadIdx.x & 63;
    int n = blockIdx.x * 4 + wave;
    if (n >= N_NODES) return;
    int head = lane >> 4;
    float adn = a_dst[n * HEADS + head];
    int beg = row_ptr[n], end = row_ptr[n + 1];
    const uint2* hq = (const uint2*)h8;

    floatx2 acc2[4];
#pragma unroll
    for (int k = 0; k < 4; ++k) acc2[k] = (floatx2){0.f, 0.f};
    float esum = 0.f;
    for (int base = beg; base < end; base += 32) {
        int m = min(32, end - base);
        int sv = (lane < m) ? src_sorted[base + lane] : 0;
        int j = 0;
        for (; j + 4 <= m; j += 4) {
            int s0 = __shfl(sv, j),     s1 = __shfl(sv, j + 1);
            int s2 = __shfl(sv, j + 2), s3 = __shfl(sv, j + 3);
            uint2 u0 = hq[(size_t)s0 * 64 + lane];
            uint2 u1 = hq[(size_t)s1 * 64 + lane];
            uint2 u2 = hq[(size_t)s2 * 64 + lane];
            uint2 u3 = hq[(size_t)s3 * 64 + lane];
            float e0 = lexp(a_src[s0 * 4 + head] + adn);
            float e1 = lexp(a_src[s1 * 4 + head] + adn);
            float e2 = lexp(a_src[s2 * 4 + head] + adn);
            float e3 = lexp(a_src[s3 * 4 + head] + adn);
            accf8p(acc2, u0, e0);
            accf8p(acc2, u1, e1);
            accf8p(acc2, u2, e2);
            accf8p(acc2, u3, e3);
            esum += (e0 + e1) + (e2 + e3);
        }
        for (; j < m; ++j) {
            int s0 = __shfl(sv, j);
            uint2 u0 = hq[(size_t)s0 * 64 + lane];
            float e0 = lexp(a_src[s0 * 4 + head] + adn);
            accf8p(acc2, u0, e0);
            esum += e0;
        }
    }
    float rinv = 1.f / (esum + 1e-16f);
    float acc[8];
#pragma unroll
    for (int k = 0; k < 4; ++k) { acc[2 * k] = acc2[k].x * rinv; acc[2 * k + 1] = acc2[k].y * rinv; }
#pragma unroll
    for (int k = 0; k < 8; ++k) {
        acc[k] += __shfl_xor(acc[k], 16);
        acc[k] += __shfl_xor(acc[k], 32);
    }
    if (lane < 16) {
        // lane holds natural channels {k*16+lane}; rc written permuted [r][ntl]
        union { uint4 v; unsigned short us[8]; } o;
#pragma unroll
        for (int k = 0; k < 8; ++k) {
            float mres = 0.25f * acc[k] + conv_b[k * 16 + lane];
            o.us[k] = bf16_bits(mres > 0.f ? mres : 0.f);
        }
        ((uint4*)rc)[(size_t)n * 16 + lane] = o.v;
    }
}

// ---------------- launcher ----------------

extern "C" void kernel_launch(void* const* d_in, const int* in_sizes, int n_in,
                              void* d_out, int out_size, void* d_ws, size_t ws_size,
                              hipStream_t stream) {
    const float* x      = (const float*)d_in[0];
    const int*   ei     = (const int*)d_in[1];
    const float* conv_w = (const float*)d_in[2];
    const float* att_s  = (const float*)d_in[3];
    const float* att_d  = (const float*)d_in[4];
    const float* conv_b = (const float*)d_in[5];
    const float* proj_w = (const float*)d_in[6];
    const float* proj_b = (const float*)d_in[7];
    const float* skip_w = (const float*)d_in[8];
    const float* skip_b = (const float*)d_in[9];
    float* out = (float*)d_out;

    char* ws = (char*)d_ws;
    size_t o = 0;
    auto alloc = [&](size_t b) { size_t c = o; o += (b + 255) & ~(size_t)255; return c; };
    __hip_bfloat16* xb16 = (__hip_bfloat16*)(ws + alloc((size_t)N_NODES * HIDDEN * 2));
    unsigned short* cwb  = (unsigned short*)(ws + alloc((size_t)2 * HIDDEN * HD * 2));
    unsigned short* pwb  = (unsigned short*)(ws + alloc((size_t)2 * HIDDEN * HIDDEN * 2));
    unsigned short* swb  = (unsigned short*)(ws + alloc((size_t)2 * HIDDEN * HIDDEN * 2));
    unsigned char* h8    = (unsigned char*)(ws + alloc((size_t)N_NODES * HD));
    float* a_src         = (float*)(ws + alloc((size_t)N_NODES * HEADS * 4));
    float* a_dst         = (float*)(ws + alloc((size_t)N_NODES * HEADS * 4));
    int* row_ptr         = (int*)(ws + alloc((size_t)(N_NODES + 1) * 4));
    int* cntfill         = (int*)(ws + alloc((size_t)2 * N_NODES * 4));
    int* cnt  = cntfill;
    int* fill = cntfill + N_NODES;
    int* src_s           = (int*)(ws + alloc((size_t)N_EDGES * 4));
    __hip_bfloat16* rc   = (__hip_bfloat16*)(ws + alloc((size_t)N_NODES * HIDDEN * 2));
    __hip_bfloat16* xb   = (__hip_bfloat16*)(ws + alloc((size_t)N_NODES * HIDDEN * 2));
    int* bsum            = (int*)(ws + alloc(64 * 4));

    const int* srcp = ei;
    const int* dstp = ei + N_EDGES;

    (void)hipMemsetAsync(cntfill, 0, (size_t)2 * N_NODES * 4, stream);

    prep_k<<<(CAST_Q + 196608 + N_EDGES + 255) / 256, 256, 0, stream>>>(
        x, (unsigned short*)xb16, conv_w, proj_w, skip_w, cwb, pwb, swb, dstp, cnt);

    const int nb = (N_NODES + 1023) / 1024;  // 49
    scan1_k<<<nb, 1024, 0, stream>>>(cnt, bsum, N_NODES);
    scan2_k<<<1, 64, 0, stream>>>(bsum, nb);
    scansc_k<<<(N_EDGES + N_NODES + 255) / 256, 256, 0, stream>>>(
        srcp, dstp, cnt, bsum, fill, src_s, row_ptr);

    const __hip_bfloat16* xc = xb16;
    for (int l = 0; l < 2; ++l) {
        gemmc_k<<<512, 256, 0, stream>>>(
            xc, cwb + (size_t)l * HIDDEN * HD,
            att_s + l * HD, att_d + l * HD, h8, a_src, a_dst, NTILES);
        msg_k<<<(N_NODES + 3) / 4, 256, 0, stream>>>(
            row_ptr, src_s, a_src, a_dst, h8, conv_b + l * HIDDEN, rc);
        if (l == 0)
            gemmp_k<__hip_bfloat16><<<512, 256, 0, stream>>>(
                rc, pwb + (size_t)l * HIDDEN * HIDDEN,
                xc, swb + (size_t)l * HIDDEN * HIDDEN,
                proj_b + l * HIDDEN, skip_b + l * HIDDEN, xb, NTILES);
        else
            gemmp_k<float><<<512, 256, 0, stream>>>(
                rc, pwb + (size_t)l * HIDDEN * HIDDEN,
                xc, swb + (size_t)l * HIDDEN * HIDDEN,
                proj_b + l * HIDDEN, skip_b + l * HIDDEN, out, NTILES);
        xc = xb;
    }
}